// Round 1
// baseline (13922.893 us; speedup 1.0000x reference)
//
#include <hip/hip_runtime.h>
#include <math.h>

#define E 256
#define NTOK 1024
#define NB 32
#define NLAYER 12
#define LN_EPS 1e-5f

// ---------------------------------------------------------------- embed
// H[r][e] = sum_{d<64} zs[r][d] * W_in[d][e] + b_in[e]
// zs[:, :, 0:63] = xs, zs[:, t, 63] = ys (0 for t == N-1)
__global__ __launch_bounds__(256) void k_embed(
    const float* __restrict__ xs, const float* __restrict__ ys,
    const float* __restrict__ W_in, const float* __restrict__ b_in,
    float* __restrict__ H)
{
    __shared__ float zs[16][64];
    const int tid = threadIdx.x;
    const int r0 = blockIdx.x * 16;
    #pragma unroll
    for (int l = 0; l < 4; ++l) {
        int lin = tid + l * 256;
        int i = lin >> 6, d = lin & 63;
        int row = r0 + i;
        int t = row & (NTOK - 1);
        float v;
        if (d < 63) v = xs[(size_t)row * 63 + d];
        else        v = (t == NTOK - 1) ? 0.f : ys[row];
        zs[i][d] = v;
    }
    __syncthreads();
    float acc[16];
    #pragma unroll
    for (int i = 0; i < 16; ++i) acc[i] = 0.f;
    for (int d = 0; d < 64; ++d) {
        float w = W_in[d * E + tid];
        #pragma unroll
        for (int i = 0; i < 16; ++i) acc[i] = fmaf(zs[i][d], w, acc[i]);
    }
    float bb = b_in[tid];
    #pragma unroll
    for (int i = 0; i < 16; ++i)
        H[(size_t)(r0 + i) * E + tid] = acc[i] + bb;
}

// ---------------------------------------------------------------- qkv
// 32 rows/block. thread: rows rg*8..+7 (rg=tid>>6), cols 4*cg..+3 (cg=tid&63)
__global__ __launch_bounds__(256, 2) void k_qkv(
    const float* __restrict__ H,
    const float* __restrict__ Wq, const float* __restrict__ Wk, const float* __restrict__ Wv,
    float* __restrict__ Q, float* __restrict__ K, float* __restrict__ V)
{
    __shared__ float Hs[32][E];   // broadcast-only reads, no pad needed
    const int tid = threadIdx.x;
    const size_t r0 = (size_t)blockIdx.x * 32;
    #pragma unroll 4
    for (int l = 0; l < 32; ++l)
        Hs[l][tid] = H[(r0 + l) * E + tid];
    __syncthreads();
    const int rg = tid >> 6;
    const int cg = tid & 63;
    float aq[8][4], ak[8][4], av[8][4];
    #pragma unroll
    for (int i = 0; i < 8; ++i)
        #pragma unroll
        for (int j = 0; j < 4; ++j) { aq[i][j] = 0.f; ak[i][j] = 0.f; av[i][j] = 0.f; }
    const float4* Wq4 = (const float4*)Wq;
    const float4* Wk4 = (const float4*)Wk;
    const float4* Wv4 = (const float4*)Wv;
    for (int k = 0; k < E; ++k) {
        float4 wq = Wq4[k * 64 + cg];
        float4 wk = Wk4[k * 64 + cg];
        float4 wv = Wv4[k * 64 + cg];
        #pragma unroll
        for (int i = 0; i < 8; ++i) {
            float h = Hs[rg * 8 + i][k];
            aq[i][0] = fmaf(h, wq.x, aq[i][0]); aq[i][1] = fmaf(h, wq.y, aq[i][1]);
            aq[i][2] = fmaf(h, wq.z, aq[i][2]); aq[i][3] = fmaf(h, wq.w, aq[i][3]);
            ak[i][0] = fmaf(h, wk.x, ak[i][0]); ak[i][1] = fmaf(h, wk.y, ak[i][1]);
            ak[i][2] = fmaf(h, wk.z, ak[i][2]); ak[i][3] = fmaf(h, wk.w, ak[i][3]);
            av[i][0] = fmaf(h, wv.x, av[i][0]); av[i][1] = fmaf(h, wv.y, av[i][1]);
            av[i][2] = fmaf(h, wv.z, av[i][2]); av[i][3] = fmaf(h, wv.w, av[i][3]);
        }
    }
    #pragma unroll
    for (int i = 0; i < 8; ++i) {
        size_t off = (r0 + rg * 8 + i) * E + cg * 4;
        *(float4*)&Q[off] = make_float4(aq[i][0], aq[i][1], aq[i][2], aq[i][3]);
        *(float4*)&K[off] = make_float4(ak[i][0], ak[i][1], ak[i][2], ak[i][3]);
        *(float4*)&V[off] = make_float4(av[i][0], av[i][1], av[i][2], av[i][3]);
    }
}

// ---------------------------------------------------------------- fused attention + residual + LN1
// block = 256 threads = one (batch, q-tile of 32 rows). O = relu(Q K^T)/n @ V, H = LN(H + O)
__global__ __launch_bounds__(256) void k_attn(
    const float* __restrict__ Q, const float* __restrict__ K, const float* __restrict__ V,
    float* __restrict__ H, const float* __restrict__ g1, const float* __restrict__ be1)
{
    __shared__ __align__(16) float Qs[32][258];   // Q tile resident; reused as x_lds for LN
    __shared__ __align__(16) float Ks[32][258];
    __shared__ __align__(16) float Ps[32][36];    // P^T : [kk][q]
    __shared__ float red[32][8][2];
    __shared__ float stats[32][2];
    const int tid = threadIdx.x;
    const int b = blockIdx.x >> 5, qt = blockIdx.x & 31;
    const size_t qbase  = ((size_t)b * NTOK + (size_t)qt * 32) * E;
    const size_t kvbase = (size_t)b * NTOK * E;
    #pragma unroll 4
    for (int l = 0; l < 32; ++l)
        Qs[l][tid] = Q[qbase + (size_t)l * E + tid];

    float o[32];
    #pragma unroll
    for (int q = 0; q < 32; ++q) o[q] = 0.f;
    const int sq = tid >> 4;   // q in {sq, sq+16}
    const int sk = tid & 15;   // k in {sk, sk+16}
    const float inv_n = 1.0f / (float)NTOK;

    for (int jt = 0; jt < 32; ++jt) {
        __syncthreads();   // prev iter fully done (covers Qs staging on iter 0)
        #pragma unroll 4
        for (int l = 0; l < 32; ++l)
            Ks[l][tid] = K[kvbase + (size_t)(jt * 32 + l) * E + tid];
        __syncthreads();
        float s00 = 0.f, s01 = 0.f, s10 = 0.f, s11 = 0.f;
        for (int e = 0; e < E; e += 2) {
            float2 qa = *(const float2*)&Qs[sq][e];
            float2 qb = *(const float2*)&Qs[sq + 16][e];
            float2 ka = *(const float2*)&Ks[sk][e];
            float2 kb = *(const float2*)&Ks[sk + 16][e];
            s00 = fmaf(qa.x, ka.x, s00); s00 = fmaf(qa.y, ka.y, s00);
            s01 = fmaf(qa.x, kb.x, s01); s01 = fmaf(qa.y, kb.y, s01);
            s10 = fmaf(qb.x, ka.x, s10); s10 = fmaf(qb.y, ka.y, s10);
            s11 = fmaf(qb.x, kb.x, s11); s11 = fmaf(qb.y, kb.y, s11);
        }
        Ps[sk][sq]           = fmaxf(s00, 0.f) * inv_n;
        Ps[sk + 16][sq]      = fmaxf(s01, 0.f) * inv_n;
        Ps[sk][sq + 16]      = fmaxf(s10, 0.f) * inv_n;
        Ps[sk + 16][sq + 16] = fmaxf(s11, 0.f) * inv_n;
        __syncthreads();
        for (int kk = 0; kk < 32; ++kk) {
            float v = V[kvbase + (size_t)(jt * 32 + kk) * E + tid];
            #pragma unroll
            for (int q4 = 0; q4 < 8; ++q4) {
                float4 p = *(const float4*)&Ps[kk][q4 * 4];  // same addr all lanes: broadcast
                o[q4 * 4 + 0] = fmaf(p.x, v, o[q4 * 4 + 0]);
                o[q4 * 4 + 1] = fmaf(p.y, v, o[q4 * 4 + 1]);
                o[q4 * 4 + 2] = fmaf(p.z, v, o[q4 * 4 + 2]);
                o[q4 * 4 + 3] = fmaf(p.w, v, o[q4 * 4 + 3]);
            }
        }
    }
    // residual + LayerNorm
    float x[32];
    #pragma unroll
    for (int q = 0; q < 32; ++q)
        x[q] = H[qbase + (size_t)q * E + tid] + o[q];
    __syncthreads();
    #pragma unroll
    for (int q = 0; q < 32; ++q) Qs[q][tid] = x[q];   // Qs reused as x_lds
    __syncthreads();
    {
        int r = tid >> 3, p = tid & 7;
        float s = 0.f, s2 = 0.f;
        for (int j = 0; j < 32; ++j) {
            float v = Qs[r][j * 8 + p];   // stride-8 interleave: ~2-3-way banks
            s += v; s2 += v * v;
        }
        red[r][p][0] = s; red[r][p][1] = s2;
    }
    __syncthreads();
    if (tid < 32) {
        float s = 0.f, s2 = 0.f;
        #pragma unroll
        for (int p = 0; p < 8; ++p) { s += red[tid][p][0]; s2 += red[tid][p][1]; }
        float mu = s * (1.f / 256.f);
        float var = s2 * (1.f / 256.f) - mu * mu;
        stats[tid][0] = mu;
        stats[tid][1] = rsqrtf(var + LN_EPS);
    }
    __syncthreads();
    float g = g1[tid], be = be1[tid];
    #pragma unroll
    for (int q = 0; q < 32; ++q)
        H[qbase + (size_t)q * E + tid] = (x[q] - stats[q][0]) * stats[q][1] * g + be;
}

// ---------------------------------------------------------------- fused MLP + residual + LN2
// 32 rows/block; thread: rows rg*8..+7, cols 4*cg..+3. Row lives in one wave -> shuffle LN.
__global__ __launch_bounds__(256, 2) void k_mlp(
    float* __restrict__ H,
    const float* __restrict__ W1, const float* __restrict__ b1,
    const float* __restrict__ W2, const float* __restrict__ b2,
    const float* __restrict__ g2, const float* __restrict__ be2)
{
    __shared__ __align__(16) float Hs[32][E];
    __shared__ __align__(16) float Ts[32][260];
    const int tid = threadIdx.x;
    const size_t r0 = (size_t)blockIdx.x * 32;
    #pragma unroll 4
    for (int l = 0; l < 32; ++l)
        Hs[l][tid] = H[(r0 + l) * E + tid];
    __syncthreads();
    const int rg = tid >> 6, cg = tid & 63;
    const float4* W14 = (const float4*)W1;
    const float4* W24 = (const float4*)W2;

    float a[8][4];
    #pragma unroll
    for (int i = 0; i < 8; ++i)
        #pragma unroll
        for (int j = 0; j < 4; ++j) a[i][j] = 0.f;
    for (int k = 0; k < E; ++k) {
        float4 w = W14[k * 64 + cg];
        #pragma unroll
        for (int i = 0; i < 8; ++i) {
            float h = Hs[rg * 8 + i][k];
            a[i][0] = fmaf(h, w.x, a[i][0]); a[i][1] = fmaf(h, w.y, a[i][1]);
            a[i][2] = fmaf(h, w.z, a[i][2]); a[i][3] = fmaf(h, w.w, a[i][3]);
        }
    }
    float4 b1v = ((const float4*)b1)[cg];
    #pragma unroll
    for (int i = 0; i < 8; ++i) {
        float4 t;
        t.x = fmaxf(a[i][0] + b1v.x, 0.f);
        t.y = fmaxf(a[i][1] + b1v.y, 0.f);
        t.z = fmaxf(a[i][2] + b1v.z, 0.f);
        t.w = fmaxf(a[i][3] + b1v.w, 0.f);
        *(float4*)&Ts[rg * 8 + i][cg * 4] = t;
    }
    __syncthreads();
    float a2[8][4];
    #pragma unroll
    for (int i = 0; i < 8; ++i)
        #pragma unroll
        for (int j = 0; j < 4; ++j) a2[i][j] = 0.f;
    for (int k = 0; k < E; ++k) {
        float4 w = W24[k * 64 + cg];
        #pragma unroll
        for (int i = 0; i < 8; ++i) {
            float t = Ts[rg * 8 + i][k];
            a2[i][0] = fmaf(t, w.x, a2[i][0]); a2[i][1] = fmaf(t, w.y, a2[i][1]);
            a2[i][2] = fmaf(t, w.z, a2[i][2]); a2[i][3] = fmaf(t, w.w, a2[i][3]);
        }
    }
    float4 b2v = ((const float4*)b2)[cg];
    float x[8][4];
    #pragma unroll
    for (int i = 0; i < 8; ++i) {
        float4 hv = *(const float4*)&Hs[rg * 8 + i][cg * 4];
        x[i][0] = hv.x + a2[i][0] + b2v.x;
        x[i][1] = hv.y + a2[i][1] + b2v.y;
        x[i][2] = hv.z + a2[i][2] + b2v.z;
        x[i][3] = hv.w + a2[i][3] + b2v.w;
    }
    float mu[8], rs[8];
    #pragma unroll
    for (int i = 0; i < 8; ++i) {
        float s  = x[i][0] + x[i][1] + x[i][2] + x[i][3];
        float s2 = x[i][0]*x[i][0] + x[i][1]*x[i][1] + x[i][2]*x[i][2] + x[i][3]*x[i][3];
        #pragma unroll
        for (int m = 1; m < 64; m <<= 1) {
            s  += __shfl_xor(s, m, 64);
            s2 += __shfl_xor(s2, m, 64);
        }
        mu[i] = s * (1.f / 256.f);
        rs[i] = rsqrtf(s2 * (1.f / 256.f) - mu[i] * mu[i] + LN_EPS);
    }
    float4 gv  = ((const float4*)g2)[cg];
    float4 bev = ((const float4*)be2)[cg];
    #pragma unroll
    for (int i = 0; i < 8; ++i) {
        float4 outv;
        outv.x = (x[i][0] - mu[i]) * rs[i] * gv.x + bev.x;
        outv.y = (x[i][1] - mu[i]) * rs[i] * gv.y + bev.y;
        outv.z = (x[i][2] - mu[i]) * rs[i] * gv.z + bev.z;
        outv.w = (x[i][3] - mu[i]) * rs[i] * gv.w + bev.w;
        *(float4*)&H[(r0 + rg * 8 + i) * E + cg * 4] = outv;
    }
}

// ---------------------------------------------------------------- readout
__global__ __launch_bounds__(256) void k_readout(
    const float* __restrict__ H, const float* __restrict__ W_out,
    const float* __restrict__ b_out, float* __restrict__ out)
{
    const int tid = threadIdx.x;
    const int lane = tid & 63;
    const int row = blockIdx.x * 4 + (tid >> 6);
    float s = 0.f;
    #pragma unroll
    for (int j = 0; j < 4; ++j)
        s += H[(size_t)row * E + j * 64 + lane] * W_out[j * 64 + lane];
    #pragma unroll
    for (int m = 1; m < 64; m <<= 1) s += __shfl_xor(s, m, 64);
    if (lane == 0) out[row] = s + b_out[0];
}

// ----------------------------------------------------------------
extern "C" void kernel_launch(void* const* d_in, const int* in_sizes, int n_in,
                              void* d_out, int out_size, void* d_ws, size_t ws_size,
                              hipStream_t stream)
{
    const float* xs    = (const float*)d_in[0];
    const float* ys    = (const float*)d_in[1];
    const float* W_in  = (const float*)d_in[2];
    const float* b_in  = (const float*)d_in[3];
    const float* Wq    = (const float*)d_in[4];
    const float* Wk    = (const float*)d_in[5];
    const float* Wv    = (const float*)d_in[6];
    const float* g1    = (const float*)d_in[7];
    const float* be1   = (const float*)d_in[8];
    const float* W1    = (const float*)d_in[9];
    const float* b1    = (const float*)d_in[10];
    const float* W2    = (const float*)d_in[11];
    const float* b2    = (const float*)d_in[12];
    const float* g2    = (const float*)d_in[13];
    const float* be2   = (const float*)d_in[14];
    const float* W_out = (const float*)d_in[15];
    const float* b_out = (const float*)d_in[16];
    (void)in_sizes; (void)n_in; (void)out_size; (void)ws_size;

    const size_t SZ = (size_t)NB * NTOK * E;   // 8,388,608 floats per buffer
    float* H = (float*)d_ws;
    float* Q = H + SZ;
    float* K = Q + SZ;
    float* V = K + SZ;

    k_embed<<<dim3(2048), dim3(256), 0, stream>>>(xs, ys, W_in, b_in, H);
    for (int i = 0; i < NLAYER; ++i) {
        const size_t mo = (size_t)i * E * E;
        const size_t vo = (size_t)i * E;
        k_qkv<<<dim3(1024), dim3(256), 0, stream>>>(H, Wq + mo, Wk + mo, Wv + mo, Q, K, V);
        k_attn<<<dim3(1024), dim3(256), 0, stream>>>(Q, K, V, H, g1 + vo, be1 + vo);
        k_mlp<<<dim3(1024), dim3(256), 0, stream>>>(H, W1 + mo, b1 + vo, W2 + mo, b2 + vo,
                                                    g2 + vo, be2 + vo);
    }
    k_readout<<<dim3((NB * NTOK) / 4), dim3(256), 0, stream>>>(H, W_out, b_out, (float*)d_out);
}

// Round 2
// 4450.659 us; speedup vs baseline: 3.1283x; 3.1283x over previous
//
#include <hip/hip_runtime.h>
#include <math.h>

#define E 256
#define NTOK 1024
#define NB 32
#define NLAYER 12
#define LN_EPS 1e-5f

typedef __attribute__((ext_vector_type(8))) short bf16x8;
typedef __attribute__((ext_vector_type(4))) float f32x4;
#define MFMA16(a, b, c) __builtin_amdgcn_mfma_f32_16x16x32_bf16(a, b, c, 0, 0, 0)

__device__ __forceinline__ ushort f2bf(float f) {
    union { float f; unsigned u; } v; v.f = f;
    return (ushort)((v.u + 0x7fffu + ((v.u >> 16) & 1u)) >> 16);
}

// ---------------------------------------------------------------- embed
__global__ __launch_bounds__(256) void k_embed(
    const float* __restrict__ xs, const float* __restrict__ ys,
    const float* __restrict__ W_in, const float* __restrict__ b_in,
    float* __restrict__ H)
{
    __shared__ float zs[16][64];
    const int tid = threadIdx.x;
    const int r0 = blockIdx.x * 16;
    #pragma unroll
    for (int l = 0; l < 4; ++l) {
        int lin = tid + l * 256;
        int i = lin >> 6, d = lin & 63;
        int row = r0 + i;
        int t = row & (NTOK - 1);
        float v;
        if (d < 63) v = xs[(size_t)row * 63 + d];
        else        v = (t == NTOK - 1) ? 0.f : ys[row];
        zs[i][d] = v;
    }
    __syncthreads();
    float acc[16];
    #pragma unroll
    for (int i = 0; i < 16; ++i) acc[i] = 0.f;
    for (int d = 0; d < 64; ++d) {
        float w = W_in[d * E + tid];
        #pragma unroll
        for (int i = 0; i < 16; ++i) acc[i] = fmaf(zs[i][d], w, acc[i]);
    }
    float bb = b_in[tid];
    #pragma unroll
    for (int i = 0; i < 16; ++i)
        H[(size_t)(r0 + i) * E + tid] = acc[i] + bb;
}

// ---------------------------------------------------------------- qkv (fp32 math, bf16 outputs)
// Q,K row-major bf16. V written TRANSPOSED: VTg[b][e][k] (register transpose, 16B stores).
__global__ __launch_bounds__(256, 2) void k_qkv(
    const float* __restrict__ H,
    const float* __restrict__ Wq, const float* __restrict__ Wk, const float* __restrict__ Wv,
    ushort* __restrict__ Qb, ushort* __restrict__ Kb, ushort* __restrict__ VTg)
{
    __shared__ float Hs[32][E];
    const int tid = threadIdx.x;
    const size_t r0 = (size_t)blockIdx.x * 32;
    #pragma unroll 4
    for (int l = 0; l < 32; ++l)
        Hs[l][tid] = H[(r0 + l) * E + tid];
    __syncthreads();
    const int rg = tid >> 6;
    const int cg = tid & 63;
    float aq[8][4], ak[8][4], av[8][4];
    #pragma unroll
    for (int i = 0; i < 8; ++i)
        #pragma unroll
        for (int j = 0; j < 4; ++j) { aq[i][j] = 0.f; ak[i][j] = 0.f; av[i][j] = 0.f; }
    const float4* Wq4 = (const float4*)Wq;
    const float4* Wk4 = (const float4*)Wk;
    const float4* Wv4 = (const float4*)Wv;
    for (int k = 0; k < E; ++k) {
        float4 wq = Wq4[k * 64 + cg];
        float4 wk = Wk4[k * 64 + cg];
        float4 wv = Wv4[k * 64 + cg];
        #pragma unroll
        for (int i = 0; i < 8; ++i) {
            float h = Hs[rg * 8 + i][k];
            aq[i][0] = fmaf(h, wq.x, aq[i][0]); aq[i][1] = fmaf(h, wq.y, aq[i][1]);
            aq[i][2] = fmaf(h, wq.z, aq[i][2]); aq[i][3] = fmaf(h, wq.w, aq[i][3]);
            ak[i][0] = fmaf(h, wk.x, ak[i][0]); ak[i][1] = fmaf(h, wk.y, ak[i][1]);
            ak[i][2] = fmaf(h, wk.z, ak[i][2]); ak[i][3] = fmaf(h, wk.w, ak[i][3]);
            av[i][0] = fmaf(h, wv.x, av[i][0]); av[i][1] = fmaf(h, wv.y, av[i][1]);
            av[i][2] = fmaf(h, wv.z, av[i][2]); av[i][3] = fmaf(h, wv.w, av[i][3]);
        }
    }
    // Q, K: row-major bf16, packed 4 per store
    #pragma unroll
    for (int i = 0; i < 8; ++i) {
        size_t off = (r0 + rg * 8 + i) * E + cg * 4;
        ushort4 uq, uk;
        uq.x = f2bf(aq[i][0]); uq.y = f2bf(aq[i][1]); uq.z = f2bf(aq[i][2]); uq.w = f2bf(aq[i][3]);
        uk.x = f2bf(ak[i][0]); uk.y = f2bf(ak[i][1]); uk.z = f2bf(ak[i][2]); uk.w = f2bf(ak[i][3]);
        *(ushort4*)&Qb[off] = uq;
        *(ushort4*)&Kb[off] = uk;
    }
    // V transposed: VTg[(b*E + col)*NTOK + krow], 8 rows packed per 16B store
    const int b   = (int)(r0 >> 10);
    const int kr0 = ((int)r0 & (NTOK - 1)) + rg * 8;
    #pragma unroll
    for (int j = 0; j < 4; ++j) {
        uint4 pk;
        pk.x = (uint)f2bf(av[0][j]) | ((uint)f2bf(av[1][j]) << 16);
        pk.y = (uint)f2bf(av[2][j]) | ((uint)f2bf(av[3][j]) << 16);
        pk.z = (uint)f2bf(av[4][j]) | ((uint)f2bf(av[5][j]) << 16);
        pk.w = (uint)f2bf(av[6][j]) | ((uint)f2bf(av[7][j]) << 16);
        size_t off = ((size_t)b * E + cg * 4 + j) * NTOK + kr0;
        *(uint4*)&VTg[off] = pk;
    }
}

// ---------------------------------------------------------------- MFMA attention + residual + LN1
// block = 256 thr (4 waves) = (batch, 64-row q-tile); wave owns 16 q-rows.
// Fragment maps (16x16x32 bf16): A: lane l elem j -> A[l&15][(l>>4)*8+j]
//                                 B: lane l elem j -> B[(l>>4)*8+j][l&15]
//                               C/D: lane l reg  r -> C[(l>>4)*4+r][l&15]
__global__ __launch_bounds__(256, 2) void k_attn(
    const ushort* __restrict__ Qb, const ushort* __restrict__ Kb, const ushort* __restrict__ VTg,
    float* __restrict__ H, const float* __restrict__ g1, const float* __restrict__ be1)
{
    __shared__ __align__(16) ushort Ks[32][264];     // padded: fragment reads bank-balanced
    __shared__ __align__(16) ushort VT[256][32];     // [e][k], 64B rows
    __shared__ __align__(16) ushort Pl[4][16][40];   // per-wave P transpose buffer
    const int tid = threadIdx.x;
    const int w  = tid >> 6, l = tid & 63;
    const int lr = l & 15, lg = l >> 4;

    // XCD swizzle: XCD x gets batches 4x..4x+3 (K+VT working set ~4MB = L2)
    const int wq  = blockIdx.x;
    const int p   = wq >> 3;
    const int batch = ((wq & 7) << 2) | (p & 3);
    const int qt  = p >> 2;

    const size_t kvbase = (size_t)batch * NTOK * E;   // elements, row-major [tok][e]
    const size_t vtbase = (size_t)batch * E * NTOK;   // elements, [e][tok]
    const int    qrow0  = qt * 64 + w * 16;
    const size_t qbase  = kvbase + (size_t)qrow0 * E;

    // Q fragments resident (16 rows x 256)
    bf16x8 qf[8];
    #pragma unroll
    for (int kk = 0; kk < 8; ++kk)
        qf[kk] = *(const bf16x8*)&Qb[qbase + (size_t)lr * E + kk * 32 + lg * 8];

    f32x4 o[16];
    #pragma unroll
    for (int nt = 0; nt < 16; ++nt) o[nt] = (f32x4){0.f, 0.f, 0.f, 0.f};

    const int skrow = tid >> 3;             // K staging: row
    const int se0   = (tid & 7) * 32;       // K staging: e start
    const float inv_n = 1.0f / (float)NTOK;

    for (int jt = 0; jt < 32; ++jt) {
        const int k0 = jt * 32;
        __syncthreads();
        // stage K-tile [32][256] -> Ks (coalesced b128)
        #pragma unroll
        for (int c = 0; c < 4; ++c) {
            bf16x8 kv = *(const bf16x8*)&Kb[kvbase + (size_t)(k0 + skrow) * E + se0 + c * 8];
            *(bf16x8*)&Ks[skrow][se0 + c * 8] = kv;
        }
        // stage VT-tile [256][32] (thread = e row)
        #pragma unroll
        for (int c = 0; c < 4; ++c) {
            bf16x8 vv = *(const bf16x8*)&VTg[vtbase + (size_t)tid * NTOK + k0 + c * 8];
            *(bf16x8*)&VT[tid][c * 8] = vv;
        }
        __syncthreads();

        // S = Q K^T  (two 16-col tiles)
        f32x4 s0 = (f32x4){0.f, 0.f, 0.f, 0.f};
        f32x4 s1 = (f32x4){0.f, 0.f, 0.f, 0.f};
        #pragma unroll
        for (int kk = 0; kk < 8; ++kk) {
            bf16x8 b0 = *(const bf16x8*)&Ks[lr][kk * 32 + lg * 8];
            bf16x8 b1 = *(const bf16x8*)&Ks[16 + lr][kk * 32 + lg * 8];
            s0 = MFMA16(qf[kk], b0, s0);
            s1 = MFMA16(qf[kk], b1, s1);
        }
        // P = relu(S)/n -> bf16, transpose via wave-private LDS
        #pragma unroll
        for (int r = 0; r < 4; ++r) {
            Pl[w][lg * 4 + r][lr]      = f2bf(fmaxf(s0[r], 0.f) * inv_n);
            Pl[w][lg * 4 + r][16 + lr] = f2bf(fmaxf(s1[r], 0.f) * inv_n);
        }
        bf16x8 pa = *(const bf16x8*)&Pl[w][lr][lg * 8];   // A-frag of P (same-wave RAW)
        // O += P V
        #pragma unroll
        for (int nt = 0; nt < 16; ++nt) {
            bf16x8 vb = *(const bf16x8*)&VT[nt * 16 + lr][lg * 8];
            o[nt] = MFMA16(pa, vb, o[nt]);
        }
    }

    // epilogue: residual + LayerNorm, fused in fragment layout
    float gg[16], bb[16];
    #pragma unroll
    for (int nt = 0; nt < 16; ++nt) {
        gg[nt] = g1[nt * 16 + lr];
        bb[nt] = be1[nt * 16 + lr];
    }
    #pragma unroll
    for (int r = 0; r < 4; ++r) {
        const int q = lg * 4 + r;
        const size_t rowbase = kvbase + (size_t)(qrow0 + q) * E;
        float xv[16];
        float s = 0.f, s2 = 0.f;
        #pragma unroll
        for (int nt = 0; nt < 16; ++nt) {
            float val = H[rowbase + nt * 16 + lr] + o[nt][r];
            xv[nt] = val;
            s += val; s2 += val * val;
        }
        #pragma unroll
        for (int m = 1; m < 16; m <<= 1) {
            s  += __shfl_xor(s, m, 64);
            s2 += __shfl_xor(s2, m, 64);
        }
        float mu = s * (1.f / 256.f);
        float rs = rsqrtf(s2 * (1.f / 256.f) - mu * mu + LN_EPS);
        #pragma unroll
        for (int nt = 0; nt < 16; ++nt)
            H[rowbase + nt * 16 + lr] = (xv[nt] - mu) * rs * gg[nt] + bb[nt];
    }
}

// ---------------------------------------------------------------- fused MLP + residual + LN2
__global__ __launch_bounds__(256, 2) void k_mlp(
    float* __restrict__ H,
    const float* __restrict__ W1, const float* __restrict__ b1,
    const float* __restrict__ W2, const float* __restrict__ b2,
    const float* __restrict__ g2, const float* __restrict__ be2)
{
    __shared__ __align__(16) float Hs[32][E];
    __shared__ __align__(16) float Ts[32][260];
    const int tid = threadIdx.x;
    const size_t r0 = (size_t)blockIdx.x * 32;
    #pragma unroll 4
    for (int l = 0; l < 32; ++l)
        Hs[l][tid] = H[(r0 + l) * E + tid];
    __syncthreads();
    const int rg = tid >> 6, cg = tid & 63;
    const float4* W14 = (const float4*)W1;
    const float4* W24 = (const float4*)W2;

    float a[8][4];
    #pragma unroll
    for (int i = 0; i < 8; ++i)
        #pragma unroll
        for (int j = 0; j < 4; ++j) a[i][j] = 0.f;
    for (int k = 0; k < E; ++k) {
        float4 w = W14[k * 64 + cg];
        #pragma unroll
        for (int i = 0; i < 8; ++i) {
            float h = Hs[rg * 8 + i][k];
            a[i][0] = fmaf(h, w.x, a[i][0]); a[i][1] = fmaf(h, w.y, a[i][1]);
            a[i][2] = fmaf(h, w.z, a[i][2]); a[i][3] = fmaf(h, w.w, a[i][3]);
        }
    }
    float4 b1v = ((const float4*)b1)[cg];
    #pragma unroll
    for (int i = 0; i < 8; ++i) {
        float4 t;
        t.x = fmaxf(a[i][0] + b1v.x, 0.f);
        t.y = fmaxf(a[i][1] + b1v.y, 0.f);
        t.z = fmaxf(a[i][2] + b1v.z, 0.f);
        t.w = fmaxf(a[i][3] + b1v.w, 0.f);
        *(float4*)&Ts[rg * 8 + i][cg * 4] = t;
    }
    __syncthreads();
    float a2[8][4];
    #pragma unroll
    for (int i = 0; i < 8; ++i)
        #pragma unroll
        for (int j = 0; j < 4; ++j) a2[i][j] = 0.f;
    for (int k = 0; k < E; ++k) {
        float4 w = W24[k * 64 + cg];
        #pragma unroll
        for (int i = 0; i < 8; ++i) {
            float t = Ts[rg * 8 + i][k];
            a2[i][0] = fmaf(t, w.x, a2[i][0]); a2[i][1] = fmaf(t, w.y, a2[i][1]);
            a2[i][2] = fmaf(t, w.z, a2[i][2]); a2[i][3] = fmaf(t, w.w, a2[i][3]);
        }
    }
    float4 b2v = ((const float4*)b2)[cg];
    float x[8][4];
    #pragma unroll
    for (int i = 0; i < 8; ++i) {
        float4 hv = *(const float4*)&Hs[rg * 8 + i][cg * 4];
        x[i][0] = hv.x + a2[i][0] + b2v.x;
        x[i][1] = hv.y + a2[i][1] + b2v.y;
        x[i][2] = hv.z + a2[i][2] + b2v.z;
        x[i][3] = hv.w + a2[i][3] + b2v.w;
    }
    float mu[8], rs[8];
    #pragma unroll
    for (int i = 0; i < 8; ++i) {
        float s  = x[i][0] + x[i][1] + x[i][2] + x[i][3];
        float s2 = x[i][0]*x[i][0] + x[i][1]*x[i][1] + x[i][2]*x[i][2] + x[i][3]*x[i][3];
        #pragma unroll
        for (int m = 1; m < 64; m <<= 1) {
            s  += __shfl_xor(s, m, 64);
            s2 += __shfl_xor(s2, m, 64);
        }
        mu[i] = s * (1.f / 256.f);
        rs[i] = rsqrtf(s2 * (1.f / 256.f) - mu[i] * mu[i] + LN_EPS);
    }
    float4 gv  = ((const float4*)g2)[cg];
    float4 bev = ((const float4*)be2)[cg];
    #pragma unroll
    for (int i = 0; i < 8; ++i) {
        float4 outv;
        outv.x = (x[i][0] - mu[i]) * rs[i] * gv.x + bev.x;
        outv.y = (x[i][1] - mu[i]) * rs[i] * gv.y + bev.y;
        outv.z = (x[i][2] - mu[i]) * rs[i] * gv.z + bev.z;
        outv.w = (x[i][3] - mu[i]) * rs[i] * gv.w + bev.w;
        *(float4*)&H[(r0 + rg * 8 + i) * E + cg * 4] = outv;
    }
}

// ---------------------------------------------------------------- readout
__global__ __launch_bounds__(256) void k_readout(
    const float* __restrict__ H, const float* __restrict__ W_out,
    const float* __restrict__ b_out, float* __restrict__ out)
{
    const int tid = threadIdx.x;
    const int lane = tid & 63;
    const int row = blockIdx.x * 4 + (tid >> 6);
    float s = 0.f;
    #pragma unroll
    for (int j = 0; j < 4; ++j)
        s += H[(size_t)row * E + j * 64 + lane] * W_out[j * 64 + lane];
    #pragma unroll
    for (int m = 1; m < 64; m <<= 1) s += __shfl_xor(s, m, 64);
    if (lane == 0) out[row] = s + b_out[0];
}

// ----------------------------------------------------------------
extern "C" void kernel_launch(void* const* d_in, const int* in_sizes, int n_in,
                              void* d_out, int out_size, void* d_ws, size_t ws_size,
                              hipStream_t stream)
{
    const float* xs    = (const float*)d_in[0];
    const float* ys    = (const float*)d_in[1];
    const float* W_in  = (const float*)d_in[2];
    const float* b_in  = (const float*)d_in[3];
    const float* Wq    = (const float*)d_in[4];
    const float* Wk    = (const float*)d_in[5];
    const float* Wv    = (const float*)d_in[6];
    const float* g1    = (const float*)d_in[7];
    const float* be1   = (const float*)d_in[8];
    const float* W1    = (const float*)d_in[9];
    const float* b1    = (const float*)d_in[10];
    const float* W2    = (const float*)d_in[11];
    const float* b2    = (const float*)d_in[12];
    const float* g2    = (const float*)d_in[13];
    const float* be2   = (const float*)d_in[14];
    const float* W_out = (const float*)d_in[15];
    const float* b_out = (const float*)d_in[16];
    (void)in_sizes; (void)n_in; (void)out_size; (void)ws_size;

    const size_t SZ = (size_t)NB * NTOK * E;   // 8,388,608 elements
    float*  H   = (float*)d_ws;                 // 32 MB fp32
    ushort* Qb  = (ushort*)(H + SZ);            // 16 MB bf16
    ushort* Kb  = Qb + SZ;                      // 16 MB bf16
    ushort* VTg = Kb + SZ;                      // 16 MB bf16, [b][e][tok]

    k_embed<<<dim3(2048), dim3(256), 0, stream>>>(xs, ys, W_in, b_in, H);
    for (int i = 0; i < NLAYER; ++i) {
        const size_t mo = (size_t)i * E * E;
        const size_t vo = (size_t)i * E;
        k_qkv<<<dim3(1024), dim3(256), 0, stream>>>(H, Wq + mo, Wk + mo, Wv + mo, Qb, Kb, VTg);
        k_attn<<<dim3(512), dim3(256), 0, stream>>>(Qb, Kb, VTg, H, g1 + vo, be1 + vo);
        k_mlp<<<dim3(1024), dim3(256), 0, stream>>>(H, W1 + mo, b1 + vo, W2 + mo, b2 + vo,
                                                    g2 + vo, be2 + vo);
    }
    k_readout<<<dim3((NB * NTOK) / 4), dim3(256), 0, stream>>>(H, W_out, b_out, (float*)d_out);
}